// Round 10
// baseline (2108.650 us; speedup 1.0000x reference)
//
#include <hip/hip_runtime.h>

typedef _Float16 half8 __attribute__((ext_vector_type(8)));
typedef float f32x4 __attribute__((ext_vector_type(4)));
typedef unsigned long long u64;
typedef u64 u64x2 __attribute__((ext_vector_type(2)));

#define MFMA16(a,b,c) __builtin_amdgcn_mfma_f32_16x16x32_f16((a),(b),(c),0,0,0)

constexpr int B_SZ = 128, S_LEN = 512, I_SZ = 512, H_SZ = 1024, O_SZ = 512;

// workspace layout (bytes)
constexpr size_t XW_OFF   = 0;                                            // f16 [S][B][H] (128 MB)
constexpr size_t X16_OFF  = XW_OFF   + (size_t)S_LEN * B_SZ * H_SZ * 2;   // f16 [B*S][I] (64 MB)
constexpr size_t WXHT_OFF = X16_OFF  + (size_t)B_SZ * S_LEN * I_SZ * 2;   // f16 [H][I]
constexpr size_t WHHT_OFF = WXHT_OFF + (size_t)H_SZ * I_SZ * 2;           // f16 [H][H]
constexpr size_t WYHT_OFF = WHHT_OFF + (size_t)H_SZ * H_SZ * 2;           // f16 [O][H]
constexpr size_t HB_OFF   = WYHT_OFF + (size_t)O_SZ * H_SZ * 2;           // u64 [8][2][32][128] (512 KB)
constexpr size_t TAG_OFF  = HB_OFF   + (size_t)8 * 8192 * 8;              // u32 [8][32 x stride16] (16 KB)

// ---------------- agent-scope (L3 coherence point) helpers — proven r2/r6/r9 ----------------
__device__ __forceinline__ u64 ag_load64(const u64* p) {
  return __hip_atomic_load(p, __ATOMIC_RELAXED, __HIP_MEMORY_SCOPE_AGENT);
}
__device__ __forceinline__ void ag_store64(u64* p, u64 v) {
  __hip_atomic_store(p, v, __ATOMIC_RELAXED, __HIP_MEMORY_SCOPE_AGENT);
}
__device__ __forceinline__ unsigned ag_load32(const unsigned* p) {
  return __hip_atomic_load(p, __ATOMIC_RELAXED, __HIP_MEMORY_SCOPE_AGENT);
}
__device__ __forceinline__ void ag_store32(unsigned* p, unsigned v) {
  __hip_atomic_store(p, v, __ATOMIC_RELAXED, __HIP_MEMORY_SCOPE_AGENT);
}

__device__ __forceinline__ float ftanh(float z) {
  // tanh(z) = 1 - 2/(e^{2z}+1); e^{2z} = 2^(2*log2e*z). Limits: +inf->1, -inf->-1.
  float e = __builtin_amdgcn_exp2f(z * 2.8853900817779268f);
  return fmaf(-2.f, __builtin_amdgcn_rcpf(e + 1.f), 1.f);
}

// ---------------- prep kernels (proven) ----------------
__global__ void k_cvt_x(const float* __restrict__ in, _Float16* __restrict__ out) {
  size_t i = ((size_t)blockIdx.x * 256 + threadIdx.x) * 8;
  float4 a = *(const float4*)(in + i);
  float4 b = *(const float4*)(in + i + 4);
  half8 h;
  h[0] = (_Float16)a.x; h[1] = (_Float16)a.y; h[2] = (_Float16)a.z; h[3] = (_Float16)a.w;
  h[4] = (_Float16)b.x; h[5] = (_Float16)b.y; h[6] = (_Float16)b.z; h[7] = (_Float16)b.w;
  *(half8*)(out + i) = h;
}

__global__ void k_transpose_cvt(const float* __restrict__ in, _Float16* __restrict__ out,
                                int K, int N) {
  int k = blockIdx.x * 256 + threadIdx.x;
  int n = blockIdx.y;
  out[(size_t)n * K + k] = (_Float16)in[(size_t)k * N + n];
}

// ---------------- phase 1: xW = x @ W_xh + b -> f16 [S][B][H] (proven) ----------------
__launch_bounds__(256, 1)
__global__ void k_xw_gemm(const _Float16* __restrict__ A,   // [65536][512]
                          const _Float16* __restrict__ BT,  // [1024][512]
                          const float* __restrict__ bias,   // [1024]
                          _Float16* __restrict__ xw)        // [S][B][H]
{
  const int m0 = blockIdx.y * 128;
  const int n0 = blockIdx.x * 128;
  __shared__ __align__(16) _Float16 la[128][72];
  __shared__ __align__(16) _Float16 lb[128][72];
  const int tid = threadIdx.x;
  const int w = tid >> 6, l = tid & 63;
  const int wr = w >> 1, wc = w & 1;
  const int cl = l & 15;
  const int kh = (l >> 4) << 3;
  const int rl = (l >> 4) << 2;

  f32x4 acc[4][4] = {};

  for (int kb = 0; kb < 512; kb += 64) {
    {
      const int r = tid >> 1, sg = tid & 1;
      const _Float16* ga = A  + (size_t)(m0 + r) * 512 + kb + sg * 32;
      const _Float16* gb = BT + (size_t)(n0 + r) * 512 + kb + sg * 32;
      _Float16* da = &la[r][sg * 32];
      _Float16* db = &lb[r][sg * 32];
      #pragma unroll
      for (int i = 0; i < 4; i++) *(half8*)(da + i * 8) = *(const half8*)(ga + i * 8);
      #pragma unroll
      for (int i = 0; i < 4; i++) *(half8*)(db + i * 8) = *(const half8*)(gb + i * 8);
    }
    __syncthreads();
    #pragma unroll
    for (int kk = 0; kk < 64; kk += 32) {
      half8 af[4], bf[4];
      #pragma unroll
      for (int mi = 0; mi < 4; mi++) af[mi] = *(const half8*)(&la[wr * 64 + mi * 16 + cl][kk + kh]);
      #pragma unroll
      for (int ni = 0; ni < 4; ni++) bf[ni] = *(const half8*)(&lb[wc * 64 + ni * 16 + cl][kk + kh]);
      #pragma unroll
      for (int mi = 0; mi < 4; mi++)
        #pragma unroll
        for (int ni = 0; ni < 4; ni++)
          acc[mi][ni] = MFMA16(af[mi], bf[ni], acc[mi][ni]);
    }
    __syncthreads();
  }

  #pragma unroll
  for (int mi = 0; mi < 4; mi++)
    #pragma unroll
    for (int ni = 0; ni < 4; ni++) {
      const int col = n0 + wc * 64 + ni * 16 + cl;
      const float bv = bias[col];
      #pragma unroll
      for (int r = 0; r < 4; r++) {
        const int m = m0 + wr * 64 + mi * 16 + rl + r;
        const int b = m >> 9;        // A rows are (b, s), S=512
        const int s = m & 511;
        xw[((size_t)(s * B_SZ + b) << 10) + col] = (_Float16)(acc[mi][ni][r] + bv);
      }
    }
}

// ---------------- phase 2+3: persistent recurrence, octet dataflow ----------------
// 8 groups (g=bid&7, 16 batch rows) x 16 wgs (j=bid>>3), 2 waves/wg. Each WAVE is
// slot p = j*2+w owning 32 H-cols; no intra-step __syncthreads. W^T rows
// 64j..64j+63 in LDS. h block p = 128 u64, MFMA-A-fragment order (r9-proven).
// Protocol: plain agent stores -> vmcnt(0) drain -> per-wave tag (stride 64B,
// avoids same-line write contention). Consumer polls all 32 tags with ONE
// vectorized load and consumes any READY OCTET of 8 blocks immediately
// (issue-then-MFMA, qa/qb pairs -> depth-2 pipeline; degenerates to r9's bulk
// path when all ready). Skew from stragglers is absorbed: only the last
// octet's observe+load+MFMA remains on the critical path.
// WAR (2 parity buffers): tag_p = t implies wave p finished reading h_{t-1}
// (induction as r6/r9). Tags memset each launch. Polls bounded -> no hang.

__device__ __forceinline__ void issueq8r(u64 (&buf)[8][2], const u64* hrow, int blk0) {
  #pragma unroll
  for (int b = 0; b < 8; b++) {
    buf[b][0] = ag_load64(hrow + ((blk0 + b) << 7));
    buf[b][1] = ag_load64(hrow + ((blk0 + b) << 7) + 1);
  }
}

__device__ __forceinline__ void mfmaq8r(const u64 (&buf)[8][2],
                                        const _Float16 (*lw)[1032], int blk0,
                                        int w, int cl, int kh, f32x4 (&acc)[2][2]) {
  #pragma unroll
  for (int b = 0; b < 8; b++) {
    const int p = blk0 + b;                       // blk0 even -> chain idx = b&1 (compile-time)
    u64x2 w2 = { buf[b][0], buf[b][1] };
    half8 a = __builtin_bit_cast(half8, w2);
    half8 b0 = *(const half8*)&lw[(w << 5) + cl][(p << 5) + kh];
    half8 b1 = *(const half8*)&lw[(w << 5) + 16 + cl][(p << 5) + kh];
    acc[0][b & 1] = MFMA16(a, b0, acc[0][b & 1]);
    acc[1][b & 1] = MFMA16(a, b1, acc[1][b & 1]);
  }
}

__device__ __forceinline__ void mfmaq_o8r(const u64 (&buf)[8][2],
                                          const _Float16* bsrc, int blk0,
                                          int kh, f32x4 (&oa)[2]) {
  #pragma unroll
  for (int b = 0; b < 8; b++) {
    const int p = blk0 + b;
    u64x2 w2 = { buf[b][0], buf[b][1] };
    half8 a = __builtin_bit_cast(half8, w2);
    half8 bv = *(const half8*)(bsrc + (p << 5) + kh);
    oa[b & 1] = MFMA16(a, bv, oa[b & 1]);
  }
}

__launch_bounds__(128, 1)
__global__ void k_rnn(const _Float16* __restrict__ xw,    // [S][B][H]
                      const _Float16* __restrict__ WhhT,  // [H][H]
                      const _Float16* __restrict__ WyhT,  // [O][H]
                      const float* __restrict__ Wby,
                      u64* __restrict__ hb,               // [8][2][32][128]
                      unsigned* __restrict__ tags,        // [8][32*16]
                      float* __restrict__ out)            // [B][O]
{
  __shared__ __align__(16) _Float16 lw[64][1032];   // W_hh^T slice (129 KB)
  __shared__ __align__(16) _Float16 stb[2][16][40]; // per-wave bounce (80B rows)

  const int bid = blockIdx.x;
  const int g = bid & 7, j = bid >> 3;     // j in 0..15
  const int tid = threadIdx.x;
  const int w = tid >> 6, l = tid & 63;
  const int p_self = (j << 1) | w;         // slot 0..31
  const int cl  = l & 15;
  const int kh  = (l >> 4) << 3;           // f16 offset in 32-col block
  const int kh2 = (l >> 4) << 1;           // u64 quad offset
  const int rl  = (l >> 4) << 2;
  const int r0  = g << 4;
  const int colbase = p_self << 5;
  unsigned* gtag = tags + (g << 9);        // 32 tags x stride 16 u32
  const unsigned* tp = gtag + ((l & 31) << 4);
  u64* hbg = hb + ((size_t)g << 13);       // 8192 u64 per group

  // load W_hh^T rows 64j..64j+63 into LDS (once)
  for (int i = tid; i < 64 * 128; i += 128) {
    const int row = i >> 7, c8 = (i & 127) << 3;
    *(half8*)&lw[row][c8] = *(const half8*)&WhhT[((size_t)((j << 6) + row) << 10) + c8];
  }
  __syncthreads();   // only barrier (prologue)

  for (int t = 0; t < 512; t++) {
    // xw_t addend for this wave's 16x32 block (plain HBM loads, overlap the poll)
    float xv[2][4];
    {
      const _Float16* p = xw + ((size_t)(t * 128 + r0 + rl) << 10) + colbase + cl;
      #pragma unroll
      for (int f = 0; f < 2; f++)
        #pragma unroll
        for (int r = 0; r < 4; r++)
          xv[f][r] = (float)p[((size_t)r << 10) + (f << 4)];
    }

    f32x4 acc[2][2] = {{{}, {}}, {{}, {}}};
    if (t > 0) {
      const u64* hrow = hbg + ((size_t)(t & 1) << 12) + (cl << 3) + kh2;
      u64 qa[8][2], qb[8][2];
      unsigned done = 0;
      for (int it = 0; done != 0xFu && it < (1 << 17); ++it) {
        unsigned tg = ag_load32(tp);
        unsigned rdy = (unsigned)__ballot((int)(tg >= (unsigned)t));
        unsigned n01 = 0, n23 = 0;
        if (!(done & 1u) && ((rdy & 0x000000FFu) == 0x000000FFu)) { issueq8r(qa, hrow, 0);  n01 |= 1u; }
        if (!(done & 2u) && ((rdy & 0x0000FF00u) == 0x0000FF00u)) { issueq8r(qb, hrow, 8);  n01 |= 2u; }
        if (n01 & 1u) mfmaq8r(qa, lw, 0,  w, cl, kh, acc);
        if (n01 & 2u) mfmaq8r(qb, lw, 8,  w, cl, kh, acc);
        if (!(done & 4u) && ((rdy & 0x00FF0000u) == 0x00FF0000u)) { issueq8r(qa, hrow, 16); n23 |= 1u; }
        if (!(done & 8u) && ((rdy & 0xFF000000u) == 0xFF000000u)) { issueq8r(qb, hrow, 24); n23 |= 2u; }
        if (n23 & 1u) mfmaq8r(qa, lw, 16, w, cl, kh, acc);
        if (n23 & 2u) mfmaq8r(qb, lw, 24, w, cl, kh, acc);
        done |= (n01 & 3u) | ((n23 & 3u) << 2);
      }
    }

    // h_{t+1} = tanh(xw_t + h_t @ W_hh): wave-local bounce, fragment-order publish
    #pragma unroll
    for (int f = 0; f < 2; f++)
      #pragma unroll
      for (int r = 0; r < 4; r++) {
        float z = xv[f][r] + acc[f][0][r] + acc[f][1][r];
        stb[w][rl + r][(f << 4) + cl] = (_Float16)ftanh(z);
      }
    asm volatile("s_waitcnt lgkmcnt(0)" ::: "memory");   // wave-local LDS RAW
    __builtin_amdgcn_sched_barrier(0);
    {
      const u64* sp = (const u64*)&stb[w][l >> 2][(l & 3) << 3];
      u64 p0 = sp[0], p1 = sp[1];
      u64* dst = hbg + ((size_t)((t + 1) & 1) << 12) + (p_self << 7)
               + ((l >> 2) << 3) + ((l & 3) << 1);
      ag_store64(dst, p0);
      ag_store64(dst + 1, p1);
    }
    asm volatile("s_waitcnt vmcnt(0)" ::: "memory");     // h at coherence point
    if (l == 0) ag_store32(gtag + (p_self << 4), (unsigned)(t + 1));
  }

  // ---------- phase 3: out = h_512 @ W_yh + b_y (h_512 in parity-0) ----------
  for (int it = 0; it < (1 << 17); ++it) {
    unsigned tg = ag_load32(tp);
    if (((unsigned)__ballot((int)(tg >= 512u))) == 0xFFFFFFFFu) break;
    __builtin_amdgcn_s_sleep(1);
  }
  __builtin_amdgcn_sched_barrier(0);
  {
    const u64* hrow = hbg + (cl << 3) + kh2;
    const int oc = (p_self << 4) + cl;          // 32 slots x 16 cols = 512
    const _Float16* bsrc = WyhT + ((size_t)oc << 10);
    f32x4 oa[2] = {{}, {}};
    u64 qa[8][2], qb[8][2];
    issueq8r(qa, hrow, 0);
    issueq8r(qb, hrow, 8);
    mfmaq_o8r(qa, bsrc, 0, kh, oa);
    issueq8r(qa, hrow, 16);
    mfmaq_o8r(qb, bsrc, 8, kh, oa);
    issueq8r(qb, hrow, 24);
    mfmaq_o8r(qa, bsrc, 16, kh, oa);
    mfmaq_o8r(qb, bsrc, 24, kh, oa);

    const float bb = Wby[oc];
    #pragma unroll
    for (int r = 0; r < 4; r++)
      out[((size_t)(r0 + rl + r) << 9) + oc] = oa[0][r] + oa[1][r] + bb;
  }
}

// ---------------- host ----------------
extern "C" void kernel_launch(void* const* d_in, const int* in_sizes, int n_in,
                              void* d_out, int out_size, void* d_ws, size_t ws_size,
                              hipStream_t stream) {
  const float* x   = (const float*)d_in[0];
  const float* Wxh = (const float*)d_in[1];
  const float* Whh = (const float*)d_in[2];
  const float* Wyh = (const float*)d_in[3];
  const float* Wbh = (const float*)d_in[4];
  const float* Wby = (const float*)d_in[5];
  float* out = (float*)d_out;

  char* ws = (char*)d_ws;
  _Float16* xw   = (_Float16*)(ws + XW_OFF);
  _Float16* x16  = (_Float16*)(ws + X16_OFF);
  _Float16* WxhT = (_Float16*)(ws + WXHT_OFF);
  _Float16* WhhT = (_Float16*)(ws + WHHT_OFF);
  _Float16* WyhT = (_Float16*)(ws + WYHT_OFF);
  u64*      hb   = (u64*)(ws + HB_OFF);
  unsigned* tags = (unsigned*)(ws + TAG_OFF);

  hipMemsetAsync(tags, 0, 8 * 32 * 16 * sizeof(unsigned), stream);

  k_cvt_x<<<16384, 256, 0, stream>>>(x, x16);
  k_transpose_cvt<<<dim3(2, 1024), 256, 0, stream>>>(Wxh, WxhT, 512, 1024);
  k_transpose_cvt<<<dim3(4, 1024), 256, 0, stream>>>(Whh, WhhT, 1024, 1024);
  k_transpose_cvt<<<dim3(4, 512),  256, 0, stream>>>(Wyh, WyhT, 1024, 512);

  k_xw_gemm<<<dim3(8, 512), 256, 0, stream>>>(x16, WxhT, Wbh, xw);

  k_rnn<<<128, 128, 0, stream>>>(xw, WhhT, WyhT, Wby, hb, tags, out);
}